// Round 1
// baseline (722.060 us; speedup 1.0000x reference)
//
#include <hip/hip_runtime.h>
#include <math.h>

typedef __attribute__((ext_vector_type(8))) short bf16x8;
typedef __attribute__((ext_vector_type(4))) float f32x4;

__device__ inline unsigned short f2bf(float f) {
    union { float f; unsigned u; } v; v.f = f;
    unsigned r = v.u + 0x7FFFu + ((v.u >> 16) & 1u);   // RNE
    return (unsigned short)(r >> 16);
}
__device__ inline float bf2f(unsigned short h) {
    union { unsigned u; float f; } v; v.u = ((unsigned)h) << 16;
    return v.f;
}

// Tiled MFMA GEMM: out[m,n] = epilogue( sum_k A[m,k]*B[n,k] + bias[n] )
// A: (M x K) row-major, AT = float (convert-on-stage) or ushort (bf16)
// B: (N x K) row-major f32 ("B^T" form), converted to bf16 on stage
// MODE 0: store bf16, MODE 1: store f32 softplus(x)+1e-3, MODE 2: store f32 x/1.5 for n<Nreal
// 128x128 tile, BK=64, 256 threads = 4 waves in 2x2, each wave 64x64 via 4x4 of 16x16x32 MFMA.
template <typename AT, int MODE>
__global__ __launch_bounds__(256) void gemm_bt(
    const AT* __restrict__ A, const float* __restrict__ Bm,
    const float* __restrict__ bias, void* __restrict__ outv,
    int M, int Npad, int Nreal, int K, int ldo)
{
    // LDS tiles padded to 72 bf16 (144 B) row stride: rows land on rotating banks,
    // 16-lane fragment reads see <=2-way conflict (free per m136), 16B-aligned.
    __shared__ __align__(16) unsigned short As[128 * 72];
    __shared__ __align__(16) unsigned short Bs[128 * 72];

    const int tid  = threadIdx.x;
    const int nblk = Npad >> 7;
    const int m0   = (blockIdx.x / nblk) << 7;
    const int n0   = (blockIdx.x % nblk) << 7;

    const int lane = tid & 63;
    const int wid  = tid >> 6;
    const int wm   = (wid & 1) * 64;   // wave m-offset within tile
    const int wn   = (wid >> 1) * 64;  // wave n-offset within tile
    const int quad = lane >> 4;        // 0..3
    const int l15  = lane & 15;

    f32x4 acc[4][4];
    #pragma unroll
    for (int i = 0; i < 4; ++i)
        #pragma unroll
        for (int j = 0; j < 4; ++j)
            acc[i][j] = f32x4{0.f, 0.f, 0.f, 0.f};

    for (int kt = 0; kt < K; kt += 64) {
        __syncthreads();   // protect previous iteration's LDS reads

        // ---- stage A tile: 128 rows x 64 cols -> bf16 LDS ----
        #pragma unroll
        for (int i = 0; i < 4; ++i) {
            int chunk = i * 256 + tid;          // 1024 chunks of 8 elems
            int row = chunk >> 3;               // 0..127
            int cc  = (chunk & 7) << 3;         // 0..56
            const AT* src = A + (size_t)(m0 + row) * K + kt + cc;
            unsigned short t[8];
            if constexpr (sizeof(AT) == 4) {
                const float4* s4 = (const float4*)src;
                float4 v0 = s4[0], v1 = s4[1];
                t[0]=f2bf(v0.x); t[1]=f2bf(v0.y); t[2]=f2bf(v0.z); t[3]=f2bf(v0.w);
                t[4]=f2bf(v1.x); t[5]=f2bf(v1.y); t[6]=f2bf(v1.z); t[7]=f2bf(v1.w);
            } else {
                const bf16x8* s8 = (const bf16x8*)src;
                bf16x8 v = s8[0];
                #pragma unroll
                for (int j = 0; j < 8; ++j) t[j] = (unsigned short)v[j];
            }
            bf16x8 val;
            #pragma unroll
            for (int j = 0; j < 8; ++j) val[j] = (short)t[j];
            *(bf16x8*)&As[row * 72 + cc] = val;
        }

        // ---- stage B tile: 128 rows (n) x 64 cols (k), f32 -> bf16, guard n>=Nreal ----
        #pragma unroll
        for (int i = 0; i < 4; ++i) {
            int chunk = i * 256 + tid;
            int row = chunk >> 3;
            int cc  = (chunk & 7) << 3;
            int n = n0 + row;
            unsigned short t[8] = {0,0,0,0,0,0,0,0};
            if (n < Nreal) {
                const float4* s4 = (const float4*)(Bm + (size_t)n * K + kt + cc);
                float4 v0 = s4[0], v1 = s4[1];
                t[0]=f2bf(v0.x); t[1]=f2bf(v0.y); t[2]=f2bf(v0.z); t[3]=f2bf(v0.w);
                t[4]=f2bf(v1.x); t[5]=f2bf(v1.y); t[6]=f2bf(v1.z); t[7]=f2bf(v1.w);
            }
            bf16x8 val;
            #pragma unroll
            for (int j = 0; j < 8; ++j) val[j] = (short)t[j];
            *(bf16x8*)&Bs[row * 72 + cc] = val;
        }
        __syncthreads();

        // ---- compute: 2 k-steps of 32 ----
        #pragma unroll
        for (int kk = 0; kk < 64; kk += 32) {
            bf16x8 af[4], bfv[4];
            #pragma unroll
            for (int mi = 0; mi < 4; ++mi)
                af[mi] = *(const bf16x8*)&As[(wm + mi*16 + l15) * 72 + kk + quad*8];
            #pragma unroll
            for (int ni = 0; ni < 4; ++ni)
                bfv[ni] = *(const bf16x8*)&Bs[(wn + ni*16 + l15) * 72 + kk + quad*8];
            #pragma unroll
            for (int mi = 0; mi < 4; ++mi)
                #pragma unroll
                for (int ni = 0; ni < 4; ++ni)
                    acc[mi][ni] = __builtin_amdgcn_mfma_f32_16x16x32_bf16(
                        af[mi], bfv[ni], acc[mi][ni], 0, 0, 0);
        }
    }

    // ---- epilogue: C/D layout col=lane&15, row=quad*4+reg (m89/m91 verified) ----
    #pragma unroll
    for (int ni = 0; ni < 4; ++ni) {
        int n = n0 + wn + ni*16 + l15;
        float bv = 0.f;
        if (MODE != 2 || n < Nreal) bv = bias[n];
        #pragma unroll
        for (int mi = 0; mi < 4; ++mi) {
            int mb = m0 + wm + mi*16 + quad*4;
            #pragma unroll
            for (int r = 0; r < 4; ++r) {
                float v = acc[mi][ni][r] + bv;
                size_t idx = (size_t)(mb + r) * ldo + n;
                if constexpr (MODE == 0) {
                    ((unsigned short*)outv)[idx] = f2bf(v);
                } else if constexpr (MODE == 1) {
                    float sp = (v > 20.f) ? v : log1pf(expf(v));
                    ((float*)outv)[idx] = sp + 1e-3f;
                } else {
                    if (n < Nreal) ((float*)outv)[idx] = v * (1.0f / 1.5f);
                }
            }
        }
    }
}

// pre[b,s,d] = f[b,d] + sum_r lr_cov[b,d,r]*nz_lr[b,s,r] + diag[b,d]*nz_diag[b,s,d]
// one block per b, 512 threads (one per d); lr coefficients held in registers,
// nz_lr[b] staged once in LDS (broadcast reads, conflict-free).
__global__ __launch_bounds__(512) void sample_kernel(
    const float* __restrict__ features, const unsigned short* __restrict__ lr_cov,
    const float* __restrict__ diag, const float* __restrict__ nz_lr,
    const float* __restrict__ nz_diag, unsigned short* __restrict__ pre,
    int S, int D)
{
    const int b = blockIdx.x;
    const int d = threadIdx.x;
    __shared__ float snz[64 * 16];

    for (int j = d; j < S * 16; j += blockDim.x)
        snz[j] = nz_lr[(size_t)b * S * 16 + j];

    float f  = features[(size_t)b * D + d];
    float dg = diag[(size_t)b * D + d];
    float lrf[16];
    const bf16x8* lp = (const bf16x8*)(lr_cov + (size_t)b * D * 16 + (size_t)d * 16);
    bf16x8 l0 = lp[0], l1 = lp[1];
    #pragma unroll
    for (int j = 0; j < 8; ++j) {
        lrf[j]     = bf2f((unsigned short)l0[j]);
        lrf[8 + j] = bf2f((unsigned short)l1[j]);
    }
    __syncthreads();

    for (int s = 0; s < S; ++s) {
        float nzd = nz_diag[((size_t)b * S + s) * D + d];
        float acc = f + dg * nzd;
        #pragma unroll
        for (int r = 0; r < 16; ++r) acc += lrf[r] * snz[s * 16 + r];
        pre[((size_t)b * S + s) * D + d] = f2bf(acc);
    }
}

extern "C" void kernel_launch(void* const* d_in, const int* in_sizes, int n_in,
                              void* d_out, int out_size, void* d_ws, size_t ws_size,
                              hipStream_t stream)
{
    const float* features = (const float*)d_in[0];
    const float* W_cov    = (const float*)d_in[1];
    const float* b_cov    = (const float*)d_in[2];
    const float* W_diag   = (const float*)d_in[3];
    const float* b_diag   = (const float*)d_in[4];
    const float* W_cls    = (const float*)d_in[5];
    const float* b_cls    = (const float*)d_in[6];
    const float* nz_diag  = (const float*)d_in[7];
    const float* nz_lr    = (const float*)d_in[8];

    const int D    = in_sizes[4];            // 512
    const int DR   = in_sizes[2];            // 8192 (= D*R, R=16)
    const int B    = in_sizes[0] / D;        // 1024
    const int S    = in_sizes[7] / (B * D);  // 64
    const int C    = in_sizes[6];            // 1000
    const int M    = B * S;                  // 65536
    const int Cpad = (C + 127) & ~127;       // 1024

    char* ws = (char*)d_ws;
    unsigned short* lr_cov = (unsigned short*)ws;                       // B*DR bf16 = 16.8 MB
    float*          diag   = (float*)(ws + (size_t)B * DR * 2);         // B*D f32  =  2.1 MB
    unsigned short* pre    = (unsigned short*)(ws + (size_t)B * DR * 2
                                                  + (size_t)B * D * 4); // M*D bf16 = 67.1 MB

    // 1) lr_cov = features @ W_cov^T + b_cov     (bf16 out, row-major B x DR)
    gemm_bt<float, 0><<<dim3((B / 128) * (DR / 128)), 256, 0, stream>>>(
        features, W_cov, b_cov, lr_cov, B, DR, DR, D, DR);

    // 2) diag = softplus(features @ W_diag^T + b_diag) + 1e-3
    gemm_bt<float, 1><<<dim3((B / 128) * (D / 128)), 256, 0, stream>>>(
        features, W_diag, b_diag, diag, B, D, D, D, D);

    // 3) pre_logits (bf16)
    sample_kernel<<<dim3(B), dim3(D), 0, stream>>>(
        features, lr_cov, diag, nz_lr, nz_diag, pre, S, D);

    // 4) logits = (pre @ W_cls^T + b_cls) / 1.5
    gemm_bt<unsigned short, 2><<<dim3((M / 128) * (Cpad / 128)), 256, 0, stream>>>(
        pre, W_cls, b_cls, d_out, M, Cpad, C, D, C);
}

// Round 2
// 568.991 us; speedup vs baseline: 1.2690x; 1.2690x over previous
//
#include <hip/hip_runtime.h>
#include <math.h>

typedef __attribute__((ext_vector_type(8))) short bf16x8;
typedef __attribute__((ext_vector_type(4))) float f32x4;
typedef __attribute__((ext_vector_type(4))) unsigned short u16x4;

__device__ inline unsigned short f2bf(float f) {
    union { float f; unsigned u; } v; v.f = f;
    unsigned r = v.u + 0x7FFFu + ((v.u >> 16) & 1u);   // RNE
    return (unsigned short)(r >> 16);
}
__device__ inline float bf2f(unsigned short h) {
    union { unsigned u; float f; } v; v.u = ((unsigned)h) << 16;
    return v.f;
}

// async 16B global -> LDS. LDS dest is wave-uniform base + lane*16 (m104).
__device__ inline void load_lds16(const void* g, void* l) {
    __builtin_amdgcn_global_load_lds(
        (const __attribute__((address_space(1))) unsigned int*)g,
        (__attribute__((address_space(3))) unsigned int*)l,
        16, 0, 0);
}

// f32 -> bf16 convert, zero-pad dst beyond nsrc. 4 elems/thread.
__global__ __launch_bounds__(256) void convert_bf16(
    const float* __restrict__ src, unsigned short* __restrict__ dst, long nsrc, long ndst)
{
    long i = ((long)blockIdx.x * 256 + threadIdx.x) * 4;
    if (i >= ndst) return;
    float4 v = make_float4(0.f, 0.f, 0.f, 0.f);
    if (i + 4 <= nsrc) v = *(const float4*)(src + i);
    u16x4 o;
    o[0] = f2bf(v.x); o[1] = f2bf(v.y); o[2] = f2bf(v.z); o[3] = f2bf(v.w);
    *(u16x4*)(dst + i) = o;
}

// Tiled MFMA GEMM, both inputs bf16, global_load_lds width-16 staging (m97 recipe).
// out[m,n] = epilogue( sum_k A[m,k]*B[n,k] + bias[n] )
// 128x128 tile, BK=64, 256 threads = 4 waves in 2x2, wave = 4x4 of 16x16x32 MFMA.
// LDS layout: row-major 128x64 bf16, per-row XOR swizzle: LDS[row][p] holds global
// chunk p^(row&7) (chunks of 8 elems) -> fragment reads land 2-way max (free, m136).
// MODE 2: f32 store v/1.5 for n<Nreal (ld=Nreal)
// MODE 3: n<nsplit -> bf16 store (ld=nsplit, bias0); else f32 softplus(v)+1e-3
//         (ld=Npad-nsplit, bias1)
template <int MODE>
__global__ __launch_bounds__(256) void gemm_bf16(
    const unsigned short* __restrict__ A, const unsigned short* __restrict__ Bm,
    const float* __restrict__ bias0, const float* __restrict__ bias1,
    void* __restrict__ out0v, void* __restrict__ out1v,
    int M, int Npad, int Nreal, int K, int nsplit)
{
    __shared__ __align__(16) unsigned short As[128 * 64];
    __shared__ __align__(16) unsigned short Bs[128 * 64];

    const int tid  = threadIdx.x;
    const int nblk = Npad >> 7;
    const int m0   = (blockIdx.x / nblk) << 7;
    const int n0   = (blockIdx.x % nblk) << 7;

    const int lane = tid & 63;
    const int wid  = tid >> 6;
    const int wm   = (wid & 1) << 6;
    const int wn   = (wid >> 1) << 6;
    const int quad = lane >> 4;
    const int l15  = lane & 15;
    const int l7   = l15 & 7;

    // staging geometry: wave w stages rows w*32..w*32+31 of both tiles,
    // 4 issues of 8 rows (64 lanes x 16B = 1024B = 8 rows of 128B).
    const int lrow = lane >> 3;                   // 0..7 within 8-row group
    const int lcol = ((lane & 7) ^ lrow) << 3;    // swizzled global col (elems)

    const unsigned short* Ab = A  + (size_t)(m0 + wid * 32 + lrow) * K + lcol;
    const unsigned short* Bb = Bm + (size_t)(n0 + wid * 32 + lrow) * K + lcol;
    unsigned short* AsW = &As[(wid * 32) * 64];
    unsigned short* BsW = &Bs[(wid * 32) * 64];

    f32x4 acc[4][4];
    #pragma unroll
    for (int i = 0; i < 4; ++i)
        #pragma unroll
        for (int j = 0; j < 4; ++j)
            acc[i][j] = f32x4{0.f, 0.f, 0.f, 0.f};

    for (int kt = 0; kt < K; kt += 64) {
        __syncthreads();   // previous iteration's LDS reads complete
        #pragma unroll
        for (int i = 0; i < 4; ++i) {
            load_lds16(Ab + (size_t)(i * 8) * K + kt, AsW + i * 8 * 64);
            load_lds16(Bb + (size_t)(i * 8) * K + kt, BsW + i * 8 * 64);
        }
        __syncthreads();   // compiler drains vmcnt before s_barrier (m97)

        #pragma unroll
        for (int kk = 0; kk < 64; kk += 32) {
            const int kq = kk >> 3;   // chunk base: 0 or 4
            bf16x8 af[4], bfv[4];
            #pragma unroll
            for (int mi = 0; mi < 4; ++mi)
                af[mi] = *(const bf16x8*)&As[(wm + mi * 16 + l15) * 64
                                             + (((kq + quad) ^ l7) << 3)];
            #pragma unroll
            for (int ni = 0; ni < 4; ++ni)
                bfv[ni] = *(const bf16x8*)&Bs[(wn + ni * 16 + l15) * 64
                                              + (((kq + quad) ^ l7) << 3)];
            #pragma unroll
            for (int mi = 0; mi < 4; ++mi)
                #pragma unroll
                for (int ni = 0; ni < 4; ++ni)
                    acc[mi][ni] = __builtin_amdgcn_mfma_f32_16x16x32_bf16(
                        af[mi], bfv[ni], acc[mi][ni], 0, 0, 0);
        }
    }

    // epilogue: C/D layout col=lane&15, row=quad*4+reg (m89/m91 verified)
    #pragma unroll
    for (int ni = 0; ni < 4; ++ni) {
        const int n = n0 + wn + ni * 16 + l15;
        if constexpr (MODE == 2) {
            const bool nok = n < Nreal;
            const float bv = nok ? bias0[n] : 0.f;
            float* o = (float*)out0v;
            #pragma unroll
            for (int mi = 0; mi < 4; ++mi) {
                const int mb = m0 + wm + mi * 16 + quad * 4;
                #pragma unroll
                for (int r = 0; r < 4; ++r) {
                    float v = (acc[mi][ni][r] + bv) * (1.0f / 1.5f);
                    if (nok) o[(size_t)(mb + r) * Nreal + n] = v;
                }
            }
        } else {  // MODE 3
            if (n0 < nsplit) {
                const float bv = bias0[n];
                unsigned short* o = (unsigned short*)out0v;
                #pragma unroll
                for (int mi = 0; mi < 4; ++mi) {
                    const int mb = m0 + wm + mi * 16 + quad * 4;
                    #pragma unroll
                    for (int r = 0; r < 4; ++r)
                        o[(size_t)(mb + r) * nsplit + n] = f2bf(acc[mi][ni][r] + bv);
                }
            } else {
                const int n1 = n - nsplit;
                const int ld1 = Npad - nsplit;
                const float bv = bias1[n1];
                float* o = (float*)out1v;
                #pragma unroll
                for (int mi = 0; mi < 4; ++mi) {
                    const int mb = m0 + wm + mi * 16 + quad * 4;
                    #pragma unroll
                    for (int r = 0; r < 4; ++r) {
                        float v = acc[mi][ni][r] + bv;
                        float sp = (v > 20.f) ? v : log1pf(expf(v));
                        o[(size_t)(mb + r) * ld1 + n1] = sp + 1e-3f;
                    }
                }
            }
        }
    }
}

// pre[b,s,d] = f[b,d] + sum_r L[b,d,r]*z[b,s,r] + diag[b,d]*nd[b,s,d], stored bf16.
// 256 threads = 2 b x 128 threads; each thread owns 4 consecutive d.
__global__ __launch_bounds__(256) void sample_kernel(
    const float* __restrict__ features, const unsigned short* __restrict__ lr_cov,
    const float* __restrict__ diag, const float* __restrict__ nz_lr,
    const float* __restrict__ nz_diag, unsigned short* __restrict__ pre,
    int S, int D)
{
    const int tid = threadIdx.x;
    const int bl  = tid >> 7;                 // 0/1
    const int b   = blockIdx.x * 2 + bl;
    const int t   = tid & 127;
    const int d0  = t << 2;

    __shared__ float snz[2][64 * 16];
    {
        const float* zsrc = nz_lr + (size_t)(blockIdx.x * 2) * S * 16;
        for (int j = tid; j < 2 * S * 16; j += 256)
            ((float*)snz)[j] = zsrc[j];
    }

    float4 f  = *(const float4*)(features + (size_t)b * D + d0);
    float4 dg = *(const float4*)(diag + (size_t)b * D + d0);
    float L[4][16];
    const unsigned short* lp = lr_cov + (size_t)b * D * 16 + (size_t)d0 * 16;
    #pragma unroll
    for (int j = 0; j < 4; ++j) {
        bf16x8 a = *(const bf16x8*)(lp + j * 16);
        bf16x8 c = *(const bf16x8*)(lp + j * 16 + 8);
        #pragma unroll
        for (int r = 0; r < 8; ++r) {
            L[j][r]     = bf2f((unsigned short)a[r]);
            L[j][8 + r] = bf2f((unsigned short)c[r]);
        }
    }
    __syncthreads();

    const float* ndp = nz_diag + (size_t)b * S * D + d0;
    unsigned short* pp = pre + (size_t)b * S * D + d0;
    for (int s = 0; s < S; ++s) {
        float4 nd = *(const float4*)(ndp + (size_t)s * D);
        float o0 = f.x + dg.x * nd.x;
        float o1 = f.y + dg.y * nd.y;
        float o2 = f.z + dg.z * nd.z;
        float o3 = f.w + dg.w * nd.w;
        const float* z = &snz[bl][s * 16];
        #pragma unroll
        for (int r = 0; r < 16; ++r) {
            float zv = z[r];
            o0 += L[0][r] * zv; o1 += L[1][r] * zv;
            o2 += L[2][r] * zv; o3 += L[3][r] * zv;
        }
        u16x4 o;
        o[0] = f2bf(o0); o[1] = f2bf(o1); o[2] = f2bf(o2); o[3] = f2bf(o3);
        *(u16x4*)(pp + (size_t)s * D) = o;
    }
}

extern "C" void kernel_launch(void* const* d_in, const int* in_sizes, int n_in,
                              void* d_out, int out_size, void* d_ws, size_t ws_size,
                              hipStream_t stream)
{
    const float* features = (const float*)d_in[0];
    const float* W_cov    = (const float*)d_in[1];
    const float* b_cov    = (const float*)d_in[2];
    const float* W_diag   = (const float*)d_in[3];
    const float* b_diag   = (const float*)d_in[4];
    const float* W_cls    = (const float*)d_in[5];
    const float* b_cls    = (const float*)d_in[6];
    const float* nz_diag  = (const float*)d_in[7];
    const float* nz_lr    = (const float*)d_in[8];

    const int D    = in_sizes[4];            // 512
    const int DR   = in_sizes[2];            // 8192
    const int B    = in_sizes[0] / D;        // 1024
    const int S    = in_sizes[7] / (B * D);  // 64
    const int C    = in_sizes[6];            // 1000
    const int M    = B * S;                  // 65536
    const int Cpad = (C + 127) & ~127;       // 1024
    const int Ncat = DR + D;                 // 8704

    // ws layout (pre overlays dead featb+wcat region): ~87 MB total
    char* ws = (char*)d_ws;
    unsigned short* lrcov = (unsigned short*)ws;                      // B*DR bf16
    float*          diag  = (float*)(ws + (size_t)B * DR * 2);        // B*D f32
    unsigned short* wclsb = (unsigned short*)((char*)diag + (size_t)B * D * 4); // Cpad*D
    char* X = (char*)wclsb + (size_t)Cpad * D * 2;
    unsigned short* featb = (unsigned short*)X;                       // B*D (dead after gemm1)
    unsigned short* wcatb = featb + (size_t)B * D;                    // Ncat*D (dead after gemm1)
    unsigned short* pre   = (unsigned short*)X;                       // M*D (overlays featb+wcatb)

    // 1) f32 -> bf16 converts
    {
        long n1 = (long)DR * D;    // W_cov
        long n2 = (long)D * D;     // W_diag
        long n3 = (long)B * D;     // features
        long n4s = (long)C * D, n4d = (long)Cpad * D;  // W_cls (zero-padded)
        convert_bf16<<<dim3((unsigned)(n1 / 1024)), 256, 0, stream>>>(W_cov, wcatb, n1, n1);
        convert_bf16<<<dim3((unsigned)(n2 / 1024)), 256, 0, stream>>>(W_diag, wcatb + n1, n2, n2);
        convert_bf16<<<dim3((unsigned)(n3 / 1024)), 256, 0, stream>>>(features, featb, n3, n3);
        convert_bf16<<<dim3((unsigned)(n4d / 1024)), 256, 0, stream>>>(W_cls, wclsb, n4s, n4d);
    }

    // 2) fused: lr_cov (bf16) + diag (softplus f32) in one GEMM over [W_cov; W_diag]
    gemm_bf16<3><<<dim3((B / 128) * (Ncat / 128)), 256, 0, stream>>>(
        featb, wcatb, b_cov, b_diag, lrcov, diag, B, Ncat, Ncat, D, DR);

    // 3) pre_logits (bf16)
    sample_kernel<<<dim3(B / 2), 256, 0, stream>>>(
        features, lrcov, diag, nz_lr, nz_diag, pre, S, D);

    // 4) logits = (pre @ W_cls^T + b_cls) / 1.5
    gemm_bf16<2><<<dim3((M / 128) * (Cpad / 128)), 256, 0, stream>>>(
        pre, wclsb, b_cls, nullptr, d_out, nullptr, M, Cpad, C, D, DR);
}

// Round 3
// 564.696 us; speedup vs baseline: 1.2787x; 1.0076x over previous
//
#include <hip/hip_runtime.h>
#include <math.h>

typedef __attribute__((ext_vector_type(8))) short bf16x8;
typedef __attribute__((ext_vector_type(4))) float f32x4;
typedef __attribute__((ext_vector_type(4))) unsigned short u16x4;

__device__ inline unsigned short f2bf(float f) {
    union { float f; unsigned u; } v; v.f = f;
    unsigned r = v.u + 0x7FFFu + ((v.u >> 16) & 1u);   // RNE
    return (unsigned short)(r >> 16);
}
__device__ inline float bf2f(unsigned short h) {
    union { unsigned u; float f; } v; v.u = ((unsigned)h) << 16;
    return v.f;
}

// async 16B global -> LDS. LDS dest is wave-uniform base + lane*16 (m104).
__device__ inline void load_lds16(const void* g, void* l) {
    __builtin_amdgcn_global_load_lds(
        (const __attribute__((address_space(1))) unsigned int*)g,
        (__attribute__((address_space(3))) unsigned int*)l,
        16, 0, 0);
}

// One-launch f32->bf16 convert of 4 segments (seg 3 zero-padded nDs..nDd).
// All segment sizes are multiples of 4.
__global__ __launch_bounds__(256) void convert_all(
    const float* __restrict__ sA, unsigned short* __restrict__ dA, long nA,
    const float* __restrict__ sB, unsigned short* __restrict__ dB, long nB,
    const float* __restrict__ sC, unsigned short* __restrict__ dC, long nC,
    const float* __restrict__ sD, unsigned short* __restrict__ dD, long nDs, long nDd)
{
    long i = ((long)blockIdx.x * 256 + threadIdx.x) * 4;
    const float* s; unsigned short* d; long nsrc;
    if (i < nA)              { s = sA + i; d = dA + i; nsrc = nA - i; }
    else if ((i -= nA) < nB) { s = sB + i; d = dB + i; nsrc = nB - i; }
    else if ((i -= nB) < nC) { s = sC + i; d = dC + i; nsrc = nC - i; }
    else if ((i -= nC) < nDd){ s = sD + i; d = dD + i; nsrc = nDs - i; }
    else return;
    float4 v = make_float4(0.f, 0.f, 0.f, 0.f);
    if (nsrc >= 4) v = *(const float4*)s;
    u16x4 o;
    o[0] = f2bf(v.x); o[1] = f2bf(v.y); o[2] = f2bf(v.z); o[3] = f2bf(v.w);
    *(u16x4*)d = o;
}

// Tiled MFMA GEMM, both inputs bf16, global_load_lds width-16 staging (m97 recipe).
// out[m,n] = epilogue( sum_k A[m,k]*B[n,k] + bias[n] )
// 128x128 tile, BK=64, 256 threads = 4 waves in 2x2, wave = 4x4 of 16x16x32 MFMA.
// LDS layout: row-major 128x64 bf16, per-row XOR swizzle: LDS[row][p] holds global
// chunk p^(row&7) (chunks of 8 elems) -> fragment ds_read_b128 lands 2-way max
// (free, m136).
// MODE 2: f32 store v/1.5 for n<Nreal (ld=Nreal)
// MODE 3: n<nsplit -> bf16 store (ld=nsplit, bias0); else f32 softplus(v)+1e-3
//         (ld=Npad-nsplit, bias1)
// SWZ: XCD-locality swizzle. Block i%8 lands on XCD i%8 (round-robin heuristic);
// give each XCD a contiguous 1/8 of m-tiles, n-tiles innermost, so each A-tile
// (128 rows x full K) is fetched into ONE XCD's L2 and reused across its 8
// n-tiles instead of being pulled by all 8 XCDs. Requires (M/128)%8==0.
template <int MODE, bool SWZ>
__global__ __launch_bounds__(256) void gemm_bf16(
    const unsigned short* __restrict__ A, const unsigned short* __restrict__ Bm,
    const float* __restrict__ bias0, const float* __restrict__ bias1,
    void* __restrict__ out0v, void* __restrict__ out1v,
    int M, int Npad, int Nreal, int K, int nsplit)
{
    __shared__ __align__(16) unsigned short As[128 * 64];
    __shared__ __align__(16) unsigned short Bs[128 * 64];

    const int tid  = threadIdx.x;
    const int nblk = Npad >> 7;
    int mt, nt;
    if constexpr (SWZ) {
        const int per = (M >> 7) >> 3;      // m-tiles per XCD
        const int x = blockIdx.x & 7;
        const int j = blockIdx.x >> 3;
        const int jm = j / nblk;
        mt = x * per + jm;
        nt = j - jm * nblk;
    } else {
        mt = blockIdx.x / nblk;
        nt = blockIdx.x - mt * nblk;
    }
    const int m0 = mt << 7;
    const int n0 = nt << 7;

    const int lane = tid & 63;
    const int wid  = tid >> 6;
    const int wm   = (wid & 1) << 6;
    const int wn   = (wid >> 1) << 6;
    const int quad = lane >> 4;
    const int l15  = lane & 15;
    const int l7   = l15 & 7;

    // staging geometry: wave w stages rows w*32..w*32+31 of both tiles,
    // 4 issues of 8 rows (64 lanes x 16B = 1024B = 8 rows of 128B).
    const int lrow = lane >> 3;                   // 0..7 within 8-row group
    const int lcol = ((lane & 7) ^ lrow) << 3;    // swizzled global col (elems)

    const unsigned short* Ab = A  + (size_t)(m0 + wid * 32 + lrow) * K + lcol;
    const unsigned short* Bb = Bm + (size_t)(n0 + wid * 32 + lrow) * K + lcol;
    unsigned short* AsW = &As[(wid * 32) * 64];
    unsigned short* BsW = &Bs[(wid * 32) * 64];

    f32x4 acc[4][4];
    #pragma unroll
    for (int i = 0; i < 4; ++i)
        #pragma unroll
        for (int j = 0; j < 4; ++j)
            acc[i][j] = f32x4{0.f, 0.f, 0.f, 0.f};

    for (int kt = 0; kt < K; kt += 64) {
        __syncthreads();   // previous iteration's LDS reads complete
        #pragma unroll
        for (int i = 0; i < 4; ++i) {
            load_lds16(Ab + (size_t)(i * 8) * K + kt, AsW + i * 8 * 64);
            load_lds16(Bb + (size_t)(i * 8) * K + kt, BsW + i * 8 * 64);
        }
        __syncthreads();   // compiler drains vmcnt before s_barrier (m97)

        #pragma unroll
        for (int kk = 0; kk < 64; kk += 32) {
            const int kq = kk >> 3;   // chunk base: 0 or 4
            bf16x8 af[4], bfv[4];
            #pragma unroll
            for (int mi = 0; mi < 4; ++mi)
                af[mi] = *(const bf16x8*)&As[(wm + mi * 16 + l15) * 64
                                             + (((kq + quad) ^ l7) << 3)];
            #pragma unroll
            for (int ni = 0; ni < 4; ++ni)
                bfv[ni] = *(const bf16x8*)&Bs[(wn + ni * 16 + l15) * 64
                                              + (((kq + quad) ^ l7) << 3)];
            #pragma unroll
            for (int mi = 0; mi < 4; ++mi)
                #pragma unroll
                for (int ni = 0; ni < 4; ++ni)
                    acc[mi][ni] = __builtin_amdgcn_mfma_f32_16x16x32_bf16(
                        af[mi], bfv[ni], acc[mi][ni], 0, 0, 0);
        }
    }

    // epilogue: C/D layout col=lane&15, row=quad*4+reg (m89/m91 verified)
    #pragma unroll
    for (int ni = 0; ni < 4; ++ni) {
        const int n = n0 + wn + ni * 16 + l15;
        if constexpr (MODE == 2) {
            const bool nok = n < Nreal;
            const float bv = nok ? bias0[n] : 0.f;
            float* o = (float*)out0v;
            #pragma unroll
            for (int mi = 0; mi < 4; ++mi) {
                const int mb = m0 + wm + mi * 16 + quad * 4;
                #pragma unroll
                for (int r = 0; r < 4; ++r) {
                    float v = (acc[mi][ni][r] + bv) * (1.0f / 1.5f);
                    if (nok) o[(size_t)(mb + r) * Nreal + n] = v;
                }
            }
        } else {  // MODE 3
            if (n0 < nsplit) {
                const float bv = bias0[n];
                unsigned short* o = (unsigned short*)out0v;
                #pragma unroll
                for (int mi = 0; mi < 4; ++mi) {
                    const int mb = m0 + wm + mi * 16 + quad * 4;
                    #pragma unroll
                    for (int r = 0; r < 4; ++r)
                        o[(size_t)(mb + r) * nsplit + n] = f2bf(acc[mi][ni][r] + bv);
                }
            } else {
                const int n1 = n - nsplit;
                const int ld1 = Npad - nsplit;
                const float bv = bias1[n1];
                float* o = (float*)out1v;
                #pragma unroll
                for (int mi = 0; mi < 4; ++mi) {
                    const int mb = m0 + wm + mi * 16 + quad * 4;
                    #pragma unroll
                    for (int r = 0; r < 4; ++r) {
                        float v = acc[mi][ni][r] + bv;
                        float sp = (v > 20.f) ? v : log1pf(expf(v));
                        o[(size_t)(mb + r) * ld1 + n1] = sp + 1e-3f;
                    }
                }
            }
        }
    }
}

// pre[b,s,d] = f[b,d] + sum_r L[b,d,r]*z[b,s,r] + diag[b,d]*nd[b,s,d], stored bf16.
// 256 threads = 2 b x 128 threads; each thread owns 4 consecutive d.
__global__ __launch_bounds__(256) void sample_kernel(
    const float* __restrict__ features, const unsigned short* __restrict__ lr_cov,
    const float* __restrict__ diag, const float* __restrict__ nz_lr,
    const float* __restrict__ nz_diag, unsigned short* __restrict__ pre,
    int S, int D)
{
    const int tid = threadIdx.x;
    const int bl  = tid >> 7;                 // 0/1
    const int b   = blockIdx.x * 2 + bl;
    const int t   = tid & 127;
    const int d0  = t << 2;

    __shared__ float snz[2][64 * 16];
    {
        const float* zsrc = nz_lr + (size_t)(blockIdx.x * 2) * S * 16;
        for (int j = tid; j < 2 * S * 16; j += 256)
            ((float*)snz)[j] = zsrc[j];
    }

    float4 f  = *(const float4*)(features + (size_t)b * D + d0);
    float4 dg = *(const float4*)(diag + (size_t)b * D + d0);
    float L[4][16];
    const unsigned short* lp = lr_cov + (size_t)b * D * 16 + (size_t)d0 * 16;
    #pragma unroll
    for (int j = 0; j < 4; ++j) {
        bf16x8 a = *(const bf16x8*)(lp + j * 16);
        bf16x8 c = *(const bf16x8*)(lp + j * 16 + 8);
        #pragma unroll
        for (int r = 0; r < 8; ++r) {
            L[j][r]     = bf2f((unsigned short)a[r]);
            L[j][8 + r] = bf2f((unsigned short)c[r]);
        }
    }
    __syncthreads();

    const float* ndp = nz_diag + (size_t)b * S * D + d0;
    unsigned short* pp = pre + (size_t)b * S * D + d0;
    for (int s = 0; s < S; ++s) {
        float4 nd = *(const float4*)(ndp + (size_t)s * D);
        float o0 = f.x + dg.x * nd.x;
        float o1 = f.y + dg.y * nd.y;
        float o2 = f.z + dg.z * nd.z;
        float o3 = f.w + dg.w * nd.w;
        const float* z = &snz[bl][s * 16];
        #pragma unroll
        for (int r = 0; r < 16; ++r) {
            float zv = z[r];
            o0 += L[0][r] * zv; o1 += L[1][r] * zv;
            o2 += L[2][r] * zv; o3 += L[3][r] * zv;
        }
        u16x4 o;
        o[0] = f2bf(o0); o[1] = f2bf(o1); o[2] = f2bf(o2); o[3] = f2bf(o3);
        *(u16x4*)(pp + (size_t)s * D) = o;
    }
}

extern "C" void kernel_launch(void* const* d_in, const int* in_sizes, int n_in,
                              void* d_out, int out_size, void* d_ws, size_t ws_size,
                              hipStream_t stream)
{
    const float* features = (const float*)d_in[0];
    const float* W_cov    = (const float*)d_in[1];
    const float* b_cov    = (const float*)d_in[2];
    const float* W_diag   = (const float*)d_in[3];
    const float* b_diag   = (const float*)d_in[4];
    const float* W_cls    = (const float*)d_in[5];
    const float* b_cls    = (const float*)d_in[6];
    const float* nz_diag  = (const float*)d_in[7];
    const float* nz_lr    = (const float*)d_in[8];

    const int D    = in_sizes[4];            // 512
    const int DR   = in_sizes[2];            // 8192
    const int B    = in_sizes[0] / D;        // 1024
    const int S    = in_sizes[7] / (B * D);  // 64
    const int C    = in_sizes[6];            // 1000
    const int M    = B * S;                  // 65536
    const int Cpad = (C + 127) & ~127;       // 1024
    const int Ncat = DR + D;                 // 8704

    // ws layout (pre overlays dead featb+wcat region): ~87 MB total
    char* ws = (char*)d_ws;
    unsigned short* lrcov = (unsigned short*)ws;                      // B*DR bf16
    float*          diag  = (float*)(ws + (size_t)B * DR * 2);        // B*D f32
    unsigned short* wclsb = (unsigned short*)((char*)diag + (size_t)B * D * 4); // Cpad*D
    char* X = (char*)wclsb + (size_t)Cpad * D * 2;
    unsigned short* featb = (unsigned short*)X;                       // B*D (dead after gemm1)
    unsigned short* wcatb = featb + (size_t)B * D;                    // Ncat*D (dead after gemm1)
    unsigned short* pre   = (unsigned short*)X;                       // M*D (overlays featb+wcatb)

    // 1) all f32 -> bf16 converts in one launch
    {
        long n1 = (long)DR * D;    // W_cov -> wcatb[0:n1]
        long n2 = (long)D * D;     // W_diag -> wcatb[n1:]
        long n3 = (long)B * D;     // features -> featb
        long n4s = (long)C * D, n4d = (long)Cpad * D;  // W_cls -> wclsb (zero-padded)
        long total = n1 + n2 + n3 + n4d;
        convert_all<<<dim3((unsigned)(total / 1024)), 256, 0, stream>>>(
            W_cov, wcatb, n1,
            W_diag, wcatb + n1, n2,
            features, featb, n3,
            W_cls, wclsb, n4s, n4d);
    }

    // 2) fused: lr_cov (bf16) + diag (softplus f32) in one GEMM over [W_cov; W_diag]
    gemm_bf16<3, false><<<dim3((B / 128) * (Ncat / 128)), 256, 0, stream>>>(
        featb, wcatb, b_cov, b_diag, lrcov, diag, B, Ncat, Ncat, D, DR);

    // 3) pre_logits (bf16)
    sample_kernel<<<dim3(B / 2), 256, 0, stream>>>(
        features, lrcov, diag, nz_lr, nz_diag, pre, S, D);

    // 4) logits = (pre @ W_cls^T + b_cls) / 1.5, XCD-swizzled for A-tile L2 reuse
    gemm_bf16<2, true><<<dim3((M / 128) * (Cpad / 128)), 256, 0, stream>>>(
        pre, wclsb, b_cls, nullptr, d_out, nullptr, M, Cpad, C, D, DR);
}